// Round 4
// baseline (190.646 us; speedup 1.0000x reference)
//
#include <hip/hip_runtime.h>
#include <hip/hip_bf16.h>
#include <math.h>

#define BB   4
#define NN   2048
#define INPT 448

typedef float f32x4 __attribute__((ext_vector_type(4)));
typedef short s16x8 __attribute__((ext_vector_type(8)));
typedef unsigned int u32;

#define MFMA(a,b,c) __builtin_amdgcn_mfma_f32_16x16x32_bf16((a),(b),(c),0,0,0)

// Fragment-layout persistent buffers (fully rewritten every launch)
__device__ __align__(16) unsigned short g_WcatF[4*8*64*8];       // (kg,jf,l) A-frag words
__device__ __align__(16) unsigned short g_WembF[8*8*64*8];       // (kg,cf,l) B-frag words
__device__ __align__(16) unsigned short g_UtF[BB*2*64*4*64*8];   // (b,dir,kk,nf,l) B-frag words, 2MB
__device__ __align__(16) float          g_G2[BB*NN*128];         // fp32 dyn*gate

// ---- fp32 -> bf16 (RNE) helpers ----
__device__ __forceinline__ u32 bf16pk(float a, float b) {
    u32 ua = __builtin_bit_cast(u32, a);
    u32 ub = __builtin_bit_cast(u32, b);
    ua += 0x7fffu + ((ua >> 16) & 1u);
    ub += 0x7fffu + ((ub >> 16) & 1u);
    return (ua >> 16) | (ub & 0xffff0000u);
}
__device__ __forceinline__ unsigned short bf16b(float a) {
    u32 ua = __builtin_bit_cast(u32, a);
    ua += 0x7fffu + ((ua >> 16) & 1u);
    return (unsigned short)(ua >> 16);
}

// ---- k0: pack weights into MFMA fragment layout ----
__global__ void k_weights(const float* __restrict__ Wf, const float* __restrict__ Wb,
                          const float* __restrict__ We) {
    int t = blockIdx.x * 256 + threadIdx.x;
    if (t < 2048) {                          // WcatF word t = (kg*8 + jf)*64 + l
        int l = t & 63, jf = (t >> 6) & 7, kg = t >> 9;
        int j  = jf * 16 + (l & 15);
        int f0 = kg * 32 + (l >> 4) * 8;
        union { u32 u[4]; s16x8 s; } r;
        #pragma unroll
        for (int e = 0; e < 8; e += 2) {
            float v0 = (j < 64) ? Wf[(f0 + e    ) * 64 + j] : Wb[(f0 + e    ) * 64 + (j - 64)];
            float v1 = (j < 64) ? Wf[(f0 + e + 1) * 64 + j] : Wb[(f0 + e + 1) * 64 + (j - 64)];
            r.u[e >> 1] = bf16pk(v0, v1);
        }
        *(s16x8*)&g_WcatF[t * 8] = r.s;
    } else if (t < 2048 + 4096) {            // WembF word idx = (kg*8 + cf)*64 + l
        int idx = t - 2048;
        int l = idx & 63, cf = (idx >> 6) & 7, kg = idx >> 9;
        int c  = cf * 16 + (l & 15);
        int k0 = kg * 32 + (l >> 4) * 8;
        union { u32 u[4]; s16x8 s; } r;
        #pragma unroll
        for (int e = 0; e < 8; e += 2)
            r.u[e >> 1] = bf16pk(We[(k0 + e) * 128 + c], We[(k0 + e + 1) * 128 + c]);
        *(s16x8*)&g_WembF[idx * 8] = r.s;
    }
}

// ---- k1: bid<256 -> UtF (frag layout); bid>=256 -> G2 ----
__global__ __launch_bounds__(256) void k_prep(const float* __restrict__ nfeat,
                                              const float* __restrict__ bemb) {
    __shared__ __align__(16) char sm[24576];
    int tid = threadIdx.x;
    int w = tid >> 6, l = tid & 63, lr = l & 15, lc = l >> 4;
    int bid = blockIdx.x;

    if (bid < 256) {
        int b = bid >> 6, nb = bid & 63;
        unsigned short* ss = (unsigned short*)sm;            // [32 n][128 f] bf16, XOR-swz
        unsigned short* ob = (unsigned short*)(sm + 8192);   // [128 j][32 n] bf16
        const float* base = nfeat + (size_t)(b * NN + nb * 32) * INPT;
        #pragma unroll
        for (int i = 0; i < 4; ++i) {                        // coalesced struct stage
            int node = w * 8 + i * 2 + (l >> 5);
            int c4 = (l & 31) * 4;
            float4 v = *(const float4*)(base + (size_t)node * INPT + 64 + c4);
            int off = node * 256 + c4 * 2; off ^= (node & 7) << 4;
            uint2 pk; pk.x = bf16pk(v.x, v.y); pk.y = bf16pk(v.z, v.w);
            *(uint2*)((char*)ss + off) = pk;
        }
        __syncthreads();
        f32x4 acc[2][2] = {};
        #pragma unroll
        for (int kg = 0; kg < 4; ++kg) {
            s16x8 a0 = *(const s16x8*)&g_WcatF[((kg * 8 + w * 2 + 0) * 64 + l) * 8];
            s16x8 a1 = *(const s16x8*)&g_WcatF[((kg * 8 + w * 2 + 1) * 64 + l) * 8];
            #pragma unroll
            for (int na = 0; na < 2; ++na) {
                int off = (na * 16 + lr) * 256 + kg * 64 + lc * 16; off ^= (lr & 7) << 4;
                s16x8 bf = *(const s16x8*)((char*)ss + off);
                acc[0][na] = MFMA(a0, bf, acc[0][na]);
                acc[1][na] = MFMA(a1, bf, acc[1][na]);
            }
        }
        #pragma unroll
        for (int ja = 0; ja < 2; ++ja)
            #pragma unroll
            for (int na = 0; na < 2; ++na)
                #pragma unroll
                for (int r = 0; r < 4; ++r) {
                    int j = w * 32 + ja * 16 + lc * 4 + r;
                    int n = na * 16 + lr;
                    ob[j * 32 + n] = bf16b(acc[ja][na][r]);
                }
        __syncthreads();
        #pragma unroll
        for (int q = 0; q < 2; ++q) {                        // frag-order write, coalesced
            int idx = q * 256 + tid;
            int dirx = idx >> 8, nf = (idx >> 6) & 3, ll = idx & 63;
            int j = dirx * 64 + nf * 16 + (ll & 15);
            int n0 = (ll >> 4) * 8;
            s16x8 v = *(const s16x8*)&ob[j * 32 + n0];
            *(s16x8*)&g_UtF[((((size_t)(b * 2 + dirx) * 64 + nb) * 4 + nf) * 64 + ll) * 8] = v;
        }
    } else {
        int bid2 = bid - 256;
        int b = bid2 >> 6, mb = bid2 & 63;
        unsigned short* ss = (unsigned short*)sm;            // [32 m][256 k] bf16, XOR-swz
        float* dyls = (float*)(sm + 16384);                  // [32 m][64] f32
        const float* base = nfeat + (size_t)(b * NN + mb * 32) * INPT;
        #pragma unroll
        for (int i = 0; i < 8; ++i) {                        // coalesced stat stage
            int row = w * 8 + i;
            float4 v = *(const float4*)(base + (size_t)row * INPT + 192 + l * 4);
            int off = row * 512 + l * 8; off ^= (row & 7) << 4;
            uint2 pk; pk.x = bf16pk(v.x, v.y); pk.y = bf16pk(v.z, v.w);
            *(uint2*)((char*)ss + off) = pk;
        }
        #pragma unroll
        for (int i = 0; i < 2; ++i) {                        // dyn stage (fp32)
            int row = w * 8 + i * 4 + lc;
            float4 v = *(const float4*)(base + (size_t)row * INPT + lr * 4);
            *(float4*)&dyls[row * 64 + lr * 4] = v;
        }
        __syncthreads();
        f32x4 acc[2][2] = {};
        #pragma unroll
        for (int kg = 0; kg < 8; ++kg) {
            s16x8 a0, a1;
            {
                int off = lr * 512 + kg * 64 + lc * 16; off ^= (lr & 7) << 4;
                a0 = *(const s16x8*)((char*)ss + off);
                a1 = *(const s16x8*)((char*)ss + off + 8192);
            }
            #pragma unroll
            for (int cfi = 0; cfi < 2; ++cfi) {
                s16x8 bf = *(const s16x8*)&g_WembF[((kg * 8 + w * 2 + cfi) * 64 + l) * 8];
                acc[cfi][0] = MFMA(a0, bf, acc[cfi][0]);
                acc[cfi][1] = MFMA(a1, bf, acc[cfi][1]);
            }
        }
        #pragma unroll
        for (int cfi = 0; cfi < 2; ++cfi) {
            int c = (w * 2 + cfi) * 16 + lr;
            float be = bemb[c];
            #pragma unroll
            for (int mf = 0; mf < 2; ++mf)
                #pragma unroll
                for (int r = 0; r < 4; ++r) {
                    int m = mf * 16 + lc * 4 + r;
                    float v = acc[cfi][mf][r] + be;
                    float g = 1.0f / (1.0f + expf(-v));
                    g_G2[(size_t)(b * NN + mb * 32 + m) * 128 + c] = g * dyls[m * 64 + (c & 63)];
                }
        }
    }
}

// ---- k2: main GEMM h = adj @ U, split-K x8, full K-slice in registers, wave-private LDS ----
__global__ __launch_bounds__(512, 8) void k_main(const float* __restrict__ adjf,
                                                 const float* __restrict__ adjb,
                                                 const float* __restrict__ biasf,
                                                 const float* __restrict__ biasb,
                                                 float* __restrict__ out) {
    __shared__ __align__(16) char sm[32768];     // 8 waves x 4KB private dbuf; reused as reduce
    int tid = threadIdx.x;
    int w = tid >> 6, l = tid & 63, lr = l & 15, lc = l >> 4;
    int bid = blockIdx.x;
    int tile = bid & 127, dir = (bid >> 7) & 1, b = bid >> 8;
    const float* adj  = dir ? adjb : adjf;
    const float* bias = dir ? biasb : biasf;
    int m0 = tile * 16;
    const unsigned short* utF = g_UtF + (size_t)(b * 2 + dir) * 131072;
    const float* ag = adj + (size_t)(b * NN + m0) * NN + w * 256;
    char* abase = sm + w * 4096;

    // Load the wave's ENTIRE 16-row x 256-col K-slice up front: 16 independent
    // dwordx4 loads, 16KB in flight per wave, one latency exposure total.
    float4 av[16];
    #pragma unroll
    for (int c = 0; c < 4; ++c)
        #pragma unroll
        for (int i = 0; i < 4; ++i)
            av[c * 4 + i] = *(const float4*)(ag + (size_t)(4 * i + lc) * NN + c * 64 + (l & 15) * 4);

    f32x4 acc[4] = {};
    #pragma unroll
    for (int c = 0; c < 4; ++c) {
        char* abuf = abase + (c & 1) * 2048;
        #pragma unroll
        for (int i = 0; i < 4; ++i) {            // convert + swizzled LDS write (wave-private)
            int row = 4 * i + lc;
            int off = row * 128 + (l & 15) * 8; off ^= (row & 7) << 4;
            uint2 pk;
            pk.x = bf16pk(av[c * 4 + i].x, av[c * 4 + i].y);
            pk.y = bf16pk(av[c * 4 + i].z, av[c * 4 + i].w);
            *(uint2*)(abuf + off) = pk;
        }
        #pragma unroll
        for (int ii = 0; ii < 2; ++ii) {
            int off = lr * 128 + ii * 64 + lc * 16; off ^= (lr & 7) << 4;
            s16x8 af = *(const s16x8*)(abuf + off);
            int kk = w * 8 + c * 2 + ii;
            #pragma unroll
            for (int nf = 0; nf < 4; ++nf) {     // B: coalesced 1KB frag words, L2-resident
                s16x8 bf = *(const s16x8*)&utF[((kk * 4 + nf) * 64 + l) * 8];
                acc[nf] = MFMA(af, bf, acc[nf]);
            }
        }
    }

    // cross-wave K reduction (reuse LDS)
    float* red = (float*)sm;
    __syncthreads();                             // all waves done with private staging regions
    #pragma unroll
    for (int nf = 0; nf < 4; ++nf)
        #pragma unroll
        for (int r = 0; r < 4; ++r)
            red[(w * 16 + nf * 4 + r) * 64 + l] = acc[nf][r];
    __syncthreads();
    if (w < 4) {
        #pragma unroll
        for (int r = 0; r < 4; ++r) {
            float s = 0.f;
            #pragma unroll
            for (int wp = 0; wp < 8; ++wp)
                s += red[(wp * 16 + w * 4 + r) * 64 + l];
            int col = w * 16 + lr;
            int m = m0 + lc * 4 + r;
            size_t o = (size_t)(b * NN + m) * 128 + dir * 64 + col;
            out[o] = (s + bias[col]) * g_G2[o];
        }
    }
}

extern "C" void kernel_launch(void* const* d_in, const int* in_sizes, int n_in,
                              void* d_out, int out_size, void* d_ws, size_t ws_size,
                              hipStream_t stream) {
    (void)in_sizes; (void)n_in; (void)d_ws; (void)ws_size; (void)out_size;
    const float* nfeat = (const float*)d_in[0];
    const float* adjf  = (const float*)d_in[1];
    const float* adjb  = (const float*)d_in[2];
    const float* Wf    = (const float*)d_in[3];
    const float* bf    = (const float*)d_in[4];
    const float* Wb    = (const float*)d_in[5];
    const float* bb    = (const float*)d_in[6];
    const float* We    = (const float*)d_in[7];
    const float* bemb  = (const float*)d_in[8];
    float* out = (float*)d_out;

    hipLaunchKernelGGL(k_weights, dim3(24),   dim3(256), 0, stream, Wf, Wb, We);
    hipLaunchKernelGGL(k_prep,    dim3(512),  dim3(256), 0, stream, nfeat, bemb);
    hipLaunchKernelGGL(k_main,    dim3(1024), dim3(512), 0, stream, adjf, adjb, bf, bb, out);
}

// Round 6
// 182.763 us; speedup vs baseline: 1.0431x; 1.0431x over previous
//
#include <hip/hip_runtime.h>
#include <hip/hip_bf16.h>
#include <math.h>

#define BB   4
#define NN   2048
#define INPT 448

typedef float f32x4 __attribute__((ext_vector_type(4)));
typedef short s16x8 __attribute__((ext_vector_type(8)));
typedef unsigned int u32;

#define MFMA(a,b,c) __builtin_amdgcn_mfma_f32_16x16x32_bf16((a),(b),(c),0,0,0)

// Fragment-layout persistent buffers (fully rewritten every launch)
__device__ __align__(16) unsigned short g_WcatF[4*8*64*8];       // (kg,jf,l) A-frag words
__device__ __align__(16) unsigned short g_WembF[8*8*64*8];       // (kg,cf,l) B-frag words
__device__ __align__(16) unsigned short g_UtF[BB*2*64*4*64*8];   // (b,dir,kk,nf,l) B-frag words, 2MB
__device__ __align__(16) float          g_G2[BB*NN*128];         // fp32 dyn*gate

// ---- fp32 -> bf16 (RNE) helpers ----
__device__ __forceinline__ u32 bf16pk(float a, float b) {
    u32 ua = __builtin_bit_cast(u32, a);
    u32 ub = __builtin_bit_cast(u32, b);
    ua += 0x7fffu + ((ua >> 16) & 1u);
    ub += 0x7fffu + ((ub >> 16) & 1u);
    return (ua >> 16) | (ub & 0xffff0000u);
}
__device__ __forceinline__ unsigned short bf16b(float a) {
    u32 ua = __builtin_bit_cast(u32, a);
    ua += 0x7fffu + ((ua >> 16) & 1u);
    return (unsigned short)(ua >> 16);
}

// ---- k0: pack weights into MFMA fragment layout ----
__global__ void k_weights(const float* __restrict__ Wf, const float* __restrict__ Wb,
                          const float* __restrict__ We) {
    int t = blockIdx.x * 256 + threadIdx.x;
    if (t < 2048) {                          // WcatF word t = (kg*8 + jf)*64 + l
        int l = t & 63, jf = (t >> 6) & 7, kg = t >> 9;
        int j  = jf * 16 + (l & 15);
        int f0 = kg * 32 + (l >> 4) * 8;
        union { u32 u[4]; s16x8 s; } r;
        #pragma unroll
        for (int e = 0; e < 8; e += 2) {
            float v0 = (j < 64) ? Wf[(f0 + e    ) * 64 + j] : Wb[(f0 + e    ) * 64 + (j - 64)];
            float v1 = (j < 64) ? Wf[(f0 + e + 1) * 64 + j] : Wb[(f0 + e + 1) * 64 + (j - 64)];
            r.u[e >> 1] = bf16pk(v0, v1);
        }
        *(s16x8*)&g_WcatF[t * 8] = r.s;
    } else if (t < 2048 + 4096) {            // WembF word idx = (kg*8 + cf)*64 + l
        int idx = t - 2048;
        int l = idx & 63, cf = (idx >> 6) & 7, kg = idx >> 9;
        int c  = cf * 16 + (l & 15);
        int k0 = kg * 32 + (l >> 4) * 8;
        union { u32 u[4]; s16x8 s; } r;
        #pragma unroll
        for (int e = 0; e < 8; e += 2)
            r.u[e >> 1] = bf16pk(We[(k0 + e) * 128 + c], We[(k0 + e + 1) * 128 + c]);
        *(s16x8*)&g_WembF[idx * 8] = r.s;
    }
}

// ---- k1: bid<256 -> UtF (frag layout); bid>=256 -> G2 ----
__global__ __launch_bounds__(256) void k_prep(const float* __restrict__ nfeat,
                                              const float* __restrict__ bemb) {
    __shared__ __align__(16) char sm[24576];
    int tid = threadIdx.x;
    int w = tid >> 6, l = tid & 63, lr = l & 15, lc = l >> 4;
    int bid = blockIdx.x;

    if (bid < 256) {
        int b = bid >> 6, nb = bid & 63;
        unsigned short* ss = (unsigned short*)sm;            // [32 n][128 f] bf16, XOR-swz
        unsigned short* ob = (unsigned short*)(sm + 8192);   // [128 j][32 n] bf16
        const float* base = nfeat + (size_t)(b * NN + nb * 32) * INPT;
        #pragma unroll
        for (int i = 0; i < 4; ++i) {                        // coalesced struct stage
            int node = w * 8 + i * 2 + (l >> 5);
            int c4 = (l & 31) * 4;
            float4 v = *(const float4*)(base + (size_t)node * INPT + 64 + c4);
            int off = node * 256 + c4 * 2; off ^= (node & 7) << 4;
            uint2 pk; pk.x = bf16pk(v.x, v.y); pk.y = bf16pk(v.z, v.w);
            *(uint2*)((char*)ss + off) = pk;
        }
        __syncthreads();
        f32x4 acc[2][2] = {};
        #pragma unroll
        for (int kg = 0; kg < 4; ++kg) {
            s16x8 a0 = *(const s16x8*)&g_WcatF[((kg * 8 + w * 2 + 0) * 64 + l) * 8];
            s16x8 a1 = *(const s16x8*)&g_WcatF[((kg * 8 + w * 2 + 1) * 64 + l) * 8];
            #pragma unroll
            for (int na = 0; na < 2; ++na) {
                int off = (na * 16 + lr) * 256 + kg * 64 + lc * 16; off ^= (lr & 7) << 4;
                s16x8 bf = *(const s16x8*)((char*)ss + off);
                acc[0][na] = MFMA(a0, bf, acc[0][na]);
                acc[1][na] = MFMA(a1, bf, acc[1][na]);
            }
        }
        #pragma unroll
        for (int ja = 0; ja < 2; ++ja)
            #pragma unroll
            for (int na = 0; na < 2; ++na)
                #pragma unroll
                for (int r = 0; r < 4; ++r) {
                    int j = w * 32 + ja * 16 + lc * 4 + r;
                    int n = na * 16 + lr;
                    ob[j * 32 + n] = bf16b(acc[ja][na][r]);
                }
        __syncthreads();
        #pragma unroll
        for (int q = 0; q < 2; ++q) {                        // frag-order write, coalesced
            int idx = q * 256 + tid;
            int dirx = idx >> 8, nf = (idx >> 6) & 3, ll = idx & 63;
            int j = dirx * 64 + nf * 16 + (ll & 15);
            int n0 = (ll >> 4) * 8;
            s16x8 v = *(const s16x8*)&ob[j * 32 + n0];
            *(s16x8*)&g_UtF[((((size_t)(b * 2 + dirx) * 64 + nb) * 4 + nf) * 64 + ll) * 8] = v;
        }
    } else {
        int bid2 = bid - 256;
        int b = bid2 >> 6, mb = bid2 & 63;
        unsigned short* ss = (unsigned short*)sm;            // [32 m][256 k] bf16, XOR-swz
        float* dyls = (float*)(sm + 16384);                  // [32 m][64] f32
        const float* base = nfeat + (size_t)(b * NN + mb * 32) * INPT;
        #pragma unroll
        for (int i = 0; i < 8; ++i) {                        // coalesced stat stage
            int row = w * 8 + i;
            float4 v = *(const float4*)(base + (size_t)row * INPT + 192 + l * 4);
            int off = row * 512 + l * 8; off ^= (row & 7) << 4;
            uint2 pk; pk.x = bf16pk(v.x, v.y); pk.y = bf16pk(v.z, v.w);
            *(uint2*)((char*)ss + off) = pk;
        }
        #pragma unroll
        for (int i = 0; i < 2; ++i) {                        // dyn stage (fp32)
            int row = w * 8 + i * 4 + lc;
            float4 v = *(const float4*)(base + (size_t)row * INPT + lr * 4);
            *(float4*)&dyls[row * 64 + lr * 4] = v;
        }
        __syncthreads();
        f32x4 acc[2][2] = {};
        #pragma unroll
        for (int kg = 0; kg < 8; ++kg) {
            s16x8 a0, a1;
            {
                int off = lr * 512 + kg * 64 + lc * 16; off ^= (lr & 7) << 4;
                a0 = *(const s16x8*)((char*)ss + off);
                a1 = *(const s16x8*)((char*)ss + off + 8192);
            }
            #pragma unroll
            for (int cfi = 0; cfi < 2; ++cfi) {
                s16x8 bf = *(const s16x8*)&g_WembF[((kg * 8 + w * 2 + cfi) * 64 + l) * 8];
                acc[cfi][0] = MFMA(a0, bf, acc[cfi][0]);
                acc[cfi][1] = MFMA(a1, bf, acc[cfi][1]);
            }
        }
        #pragma unroll
        for (int cfi = 0; cfi < 2; ++cfi) {
            int c = (w * 2 + cfi) * 16 + lr;
            float be = bemb[c];
            #pragma unroll
            for (int mf = 0; mf < 2; ++mf)
                #pragma unroll
                for (int r = 0; r < 4; ++r) {
                    int m = mf * 16 + lc * 4 + r;
                    float v = acc[cfi][mf][r] + be;
                    float g = 1.0f / (1.0f + expf(-v));
                    g_G2[(size_t)(b * NN + mb * 32 + m) * 128 + c] = g * dyls[m * 64 + (c & 63)];
                }
        }
    }
}

// ---- asm-forced deep-prefetch primitives ----
#define GLOADO(dst, p, ofs) \
    asm volatile("global_load_dwordx4 %0, %1, off offset:" #ofs \
                 : "=v"(dst) : "v"(p) : "memory")

#define STG1(abuf, i, AV) do { \
    int row_ = 4 * (i) + lc; \
    int off_ = row_ * 128 + lr * 8; off_ ^= (row_ & 7) << 4; \
    uint2 pk_; pk_.x = bf16pk((AV)[0], (AV)[1]); pk_.y = bf16pk((AV)[2], (AV)[3]); \
    *(uint2*)((abuf) + off_) = pk_; \
} while (0)

#define CHUNK(c, vmstr, A0, A1, A2, A3) do { \
    asm volatile("s_waitcnt vmcnt(" vmstr ")" \
                 : "+v"(A0), "+v"(A1), "+v"(A2), "+v"(A3) : : "memory"); \
    char* abuf_ = abase + ((c) & 1) * 2048; \
    STG1(abuf_, 0, A0); STG1(abuf_, 1, A1); STG1(abuf_, 2, A2); STG1(abuf_, 3, A3); \
    _Pragma("unroll") \
    for (int ii = 0; ii < 2; ++ii) { \
        int off_ = lr * 128 + ii * 64 + lc * 16; off_ ^= (lr & 7) << 4; \
        s16x8 af_ = *(const s16x8*)(abuf_ + off_); \
        int kk_ = w * 8 + (c) * 2 + ii; \
        _Pragma("unroll") \
        for (int nf = 0; nf < 4; ++nf) { \
            s16x8 bv_ = *(const s16x8*)&utF[((kk_ * 4 + nf) * 64 + l) * 8]; \
            acc[nf] = MFMA(af_, bv_, acc[nf]); \
        } \
    } \
} while (0)

// ---- k2: main GEMM h = adj @ U, split-K x8, asm-pipelined 16KB/wave A-prefetch ----
__global__ __launch_bounds__(512, 2) void k_main(const float* __restrict__ adjf,
                                                 const float* __restrict__ adjb,
                                                 const float* __restrict__ biasf,
                                                 const float* __restrict__ biasb,
                                                 float* __restrict__ out) {
    __shared__ __align__(16) char sm[32768];     // 8 waves x 4KB private dbuf; reused as reduce
    int tid = threadIdx.x;
    int w = tid >> 6, l = tid & 63, lr = l & 15, lc = l >> 4;
    int bid = blockIdx.x;
    int tile = bid & 127, dir = (bid >> 7) & 1, b = bid >> 8;
    const float* adj  = dir ? adjb : adjf;
    const float* bias = dir ? biasb : biasf;
    int m0 = tile * 16;
    const unsigned short* utF = g_UtF + (size_t)(b * 2 + dir) * 131072;
    const float* ag = adj + (size_t)(b * NN + m0) * NN + w * 256;
    char* abase = sm + w * 4096;

    // 4 row-group base addresses; chunks are offset: immediates (256B apart)
    const float* ba0 = ag + (size_t)(lc     ) * NN + lr * 4;
    const float* ba1 = ag + (size_t)(lc +  4) * NN + lr * 4;
    const float* ba2 = ag + (size_t)(lc +  8) * NN + lr * 4;
    const float* ba3 = ag + (size_t)(lc + 12) * NN + lr * 4;

    // Issue the wave's ENTIRE 16-row x 256-col K-slice: 16 asm loads, 16KB in flight.
    f32x4 av[16];
    GLOADO(av[0],  ba0, 0);   GLOADO(av[1],  ba1, 0);   GLOADO(av[2],  ba2, 0);   GLOADO(av[3],  ba3, 0);
    GLOADO(av[4],  ba0, 256); GLOADO(av[5],  ba1, 256); GLOADO(av[6],  ba2, 256); GLOADO(av[7],  ba3, 256);
    GLOADO(av[8],  ba0, 512); GLOADO(av[9],  ba1, 512); GLOADO(av[10], ba2, 512); GLOADO(av[11], ba3, 512);
    GLOADO(av[12], ba0, 768); GLOADO(av[13], ba1, 768); GLOADO(av[14], ba2, 768); GLOADO(av[15], ba3, 768);

    f32x4 acc[4] = {};
    CHUNK(0, "12", av[0],  av[1],  av[2],  av[3]);
    CHUNK(1, "8",  av[4],  av[5],  av[6],  av[7]);
    CHUNK(2, "4",  av[8],  av[9],  av[10], av[11]);
    CHUNK(3, "0",  av[12], av[13], av[14], av[15]);

    // cross-wave K reduction (reuse LDS)
    float* red = (float*)sm;
    __syncthreads();                             // all waves done with private staging regions
    #pragma unroll
    for (int nf = 0; nf < 4; ++nf)
        #pragma unroll
        for (int r = 0; r < 4; ++r)
            red[(w * 16 + nf * 4 + r) * 64 + l] = acc[nf][r];
    __syncthreads();
    if (w < 4) {
        #pragma unroll
        for (int r = 0; r < 4; ++r) {
            float s = 0.f;
            #pragma unroll
            for (int wp = 0; wp < 8; ++wp)
                s += red[(wp * 16 + w * 4 + r) * 64 + l];
            int col = w * 16 + lr;
            int m = m0 + lc * 4 + r;
            size_t o = (size_t)(b * NN + m) * 128 + dir * 64 + col;
            out[o] = (s + bias[col]) * g_G2[o];
        }
    }
}

extern "C" void kernel_launch(void* const* d_in, const int* in_sizes, int n_in,
                              void* d_out, int out_size, void* d_ws, size_t ws_size,
                              hipStream_t stream) {
    (void)in_sizes; (void)n_in; (void)d_ws; (void)ws_size; (void)out_size;
    const float* nfeat = (const float*)d_in[0];
    const float* adjf  = (const float*)d_in[1];
    const float* adjb  = (const float*)d_in[2];
    const float* Wf    = (const float*)d_in[3];
    const float* bf    = (const float*)d_in[4];
    const float* Wb    = (const float*)d_in[5];
    const float* bb    = (const float*)d_in[6];
    const float* We    = (const float*)d_in[7];
    const float* bemb  = (const float*)d_in[8];
    float* out = (float*)d_out;

    hipLaunchKernelGGL(k_weights, dim3(24),   dim3(256), 0, stream, Wf, Wb, We);
    hipLaunchKernelGGL(k_prep,    dim3(512),  dim3(256), 0, stream, nfeat, bemb);
    hipLaunchKernelGGL(k_main,    dim3(1024), dim3(512), 0, stream, adjf, adjb, bf, bb, out);
}